// Round 3
// baseline (6866.515 us; speedup 1.0000x reference)
//
#include <hip/hip_runtime.h>

#define NAGENTS 32
#define NOBSV   2
#define H1D     128
#define HXD     64
#define NACTD   5
#define TBATCH  8
#define NTHREADS 256
#define HSTRIDE (NAGENTS * HXD + 4)   // 2052 floats per batch row (pad 4 -> bank spread)

// 256 threads = 4 waves. Wave w owns agents 8w..8w+7.
// Lane decomposition: lane = og*8 + lb, og in 0..7 (8-output chunk), lb in 0..7 (batch).
// Phase-1/3 thread decomposition: tid = p_a*8 + p_b == (wave*8+og)*8 + lb.
// LDS: s_obs 2.1 KB + s_hid 65.7 KB -> ~67 KB -> 2 blocks/CU.
__global__ __launch_bounds__(NTHREADS, 2) void qnet_fused(
    const float* __restrict__ obs,
    const float* __restrict__ W1, const float* __restrict__ b1,
    const float* __restrict__ W2, const float* __restrict__ b2,
    const float* __restrict__ Wc, const float* __restrict__ bc,
    const float* __restrict__ Wd, const float* __restrict__ bd,
    float* __restrict__ out)
{
    __shared__ float s_obs[TBATCH][NAGENTS * 2 + 2];
    __shared__ float s_hid[TBATCH * HSTRIDE];

    const int tid  = threadIdx.x;
    const int wave = tid >> 6;        // 0..3
    const int lane = tid & 63;
    const int lb   = lane & 7;        // batch-in-tile
    const int og   = lane >> 3;       // out-group (8 outputs)
    const int b0   = blockIdx.x * TBATCH;

    // ---- load obs tile: 8 x 32 x 2 floats = 512 floats, one float2/thread ----
    {
        const float2* src = reinterpret_cast<const float2*>(obs + (size_t)b0 * (NAGENTS * NOBSV));
        float2 v = src[tid];
        s_obs[tid >> 5][(tid & 31) * 2 + 0] = v.x;
        s_obs[tid >> 5][(tid & 31) * 2 + 1] = v.y;
    }
    __syncthreads();

    // ---- phase 1: neighbor mask for (p_a, p_b) in FLOAT64, matching the
    //      numpy-f64 reference bit-exactly. All intermediates (<~30 mantissa
    //      bits) are EXACT in f64, so op-fusion cannot change the compares. ----
    const int p_a = tid >> 3;    // 0..31
    const int p_b = tid & 7;     // 0..7
    unsigned int bits = 0u;
    float Jf;
    {
        const double xi = (double)s_obs[p_b][p_a * 2 + 0] * 2.0;  // scales=[GRID_X-1,GRID_Y-1]
        const double yi = (double)s_obs[p_b][p_a * 2 + 1] * 6.0;
        #pragma unroll
        for (int j = 0; j < NAGENTS; ++j) {
            double xj = (double)s_obs[p_b][j * 2 + 0] * 2.0;
            double yj = (double)s_obs[p_b][j * 2 + 1] * 6.0;
            double d = fabs(xi - xj) + fabs(yi - yj);
            if (d > 0.0 && d < 2.0) bits |= (1u << j);
        }
        Jf = fmaxf((float)__popc(bits), 1.0f);
    }

    // ---- phase 2: encoder MLP -> s_hid (f32). Wave w, iter ai -> agent 8w+ai. ----
    #pragma unroll 1
    for (int ai = 0; ai < 8; ++ai) {
        const int a = wave * 8 + ai;
        const float o0 = s_obs[lb][a * 2 + 0];
        const float o1 = s_obs[lb][a * 2 + 1];
        const float* __restrict__ w1p = W1 + a * (NOBSV * H1D);
        const float* __restrict__ b1p = b1 + a * H1D;
        const float* __restrict__ w2p = W2 + a * (H1D * HXD) + og * 8;
        const float* __restrict__ b2p = b2 + a * HXD + og * 8;
        float acc[8];
        {
            float4 bv0 = *reinterpret_cast<const float4*>(b2p + 0);
            float4 bv1 = *reinterpret_cast<const float4*>(b2p + 4);
            acc[0] = bv0.x; acc[1] = bv0.y; acc[2] = bv0.z; acc[3] = bv0.w;
            acc[4] = bv1.x; acc[5] = bv1.y; acc[6] = bv1.z; acc[7] = bv1.w;
        }
        #pragma unroll 4
        for (int k = 0; k < H1D; ++k) {
            float w0  = w1p[k];
            float w1v = w1p[H1D + k];
            float bb  = b1p[k];
            float h = fmaxf(fmaf(o1, w1v, fmaf(o0, w0, bb)), 0.0f);
            const float* wr = w2p + k * HXD;
            float4 wv0 = *reinterpret_cast<const float4*>(wr + 0);
            float4 wv1 = *reinterpret_cast<const float4*>(wr + 4);
            acc[0] = fmaf(h, wv0.x, acc[0]);
            acc[1] = fmaf(h, wv0.y, acc[1]);
            acc[2] = fmaf(h, wv0.z, acc[2]);
            acc[3] = fmaf(h, wv0.w, acc[3]);
            acc[4] = fmaf(h, wv1.x, acc[4]);
            acc[5] = fmaf(h, wv1.y, acc[5]);
            acc[6] = fmaf(h, wv1.z, acc[6]);
            acc[7] = fmaf(h, wv1.w, acc[7]);
        }
        float* dst = &s_hid[lb * HSTRIDE + a * HXD + og * 8];
        *reinterpret_cast<float4*>(dst + 0) =
            make_float4(fmaxf(acc[0],0.f), fmaxf(acc[1],0.f), fmaxf(acc[2],0.f), fmaxf(acc[3],0.f));
        *reinterpret_cast<float4*>(dst + 4) =
            make_float4(fmaxf(acc[4],0.f), fmaxf(acc[5],0.f), fmaxf(acc[6],0.f), fmaxf(acc[7],0.f));
    }
    __syncthreads();

    // ---- phase 3: comms for (p_a, p_b). Skip-zero masked sum == reference
    //      include-zero sum exactly (hidden >= 0). True division by J. ----
    float cm[HXD];
    #pragma unroll
    for (int o = 0; o < HXD; ++o) cm[o] = 0.0f;
    #pragma unroll 1
    for (int j = 0; j < NAGENTS; ++j) {
        if ((bits >> j) & 1u) {
            const float4* hp = reinterpret_cast<const float4*>(&s_hid[p_b * HSTRIDE + j * HXD]);
            #pragma unroll
            for (int c = 0; c < 16; ++c) {
                float4 v = hp[c];
                cm[c*4+0] += v.x;
                cm[c*4+1] += v.y;
                cm[c*4+2] += v.z;
                cm[c*4+3] += v.w;
            }
        }
    }
    #pragma unroll
    for (int o = 0; o < HXD; ++o) cm[o] /= Jf;

    // ---- phase 4: comm MLP (tanh) + decoder. comms fetched via wave shuffle
    //      from owner lane (ai*8 + lb) — no LDS staging, no barriers. ----
    #pragma unroll 1
    for (int ai = 0; ai < 8; ++ai) {
        const int a = wave * 8 + ai;
        const float* __restrict__ wcp = Wc + a * (2 * HXD * HXD) + og * 8;
        const float* __restrict__ bcp = bc + a * HXD + og * 8;
        float acc[8];
        {
            float4 bv0 = *reinterpret_cast<const float4*>(bcp + 0);
            float4 bv1 = *reinterpret_cast<const float4*>(bcp + 4);
            acc[0] = bv0.x; acc[1] = bv0.y; acc[2] = bv0.z; acc[3] = bv0.w;
            acc[4] = bv1.x; acc[5] = bv1.y; acc[6] = bv1.z; acc[7] = bv1.w;
        }
        const int hbase = lb * HSTRIDE + a * HXD;
        // k = 0..63 : comm_input first half = hidden (f32 from LDS, broadcast)
        #pragma unroll 4
        for (int k = 0; k < HXD; ++k) {
            const float ci = s_hid[hbase + k];
            const float* wr = wcp + k * HXD;
            float4 wv0 = *reinterpret_cast<const float4*>(wr + 0);
            float4 wv1 = *reinterpret_cast<const float4*>(wr + 4);
            acc[0] = fmaf(ci, wv0.x, acc[0]);
            acc[1] = fmaf(ci, wv0.y, acc[1]);
            acc[2] = fmaf(ci, wv0.z, acc[2]);
            acc[3] = fmaf(ci, wv0.w, acc[3]);
            acc[4] = fmaf(ci, wv1.x, acc[4]);
            acc[5] = fmaf(ci, wv1.y, acc[5]);
            acc[6] = fmaf(ci, wv1.z, acc[6]);
            acc[7] = fmaf(ci, wv1.w, acc[7]);
        }
        // k = 64..127 : second half = comms, shuffled from owner lane ai*8+lb.
        // Fully unrolled so cm[k] is a static register index.
        const int srcLane = ai * 8 + lb;
        #pragma unroll
        for (int k = 0; k < HXD; ++k) {
            const float ci = __shfl(cm[k], srcLane, 64);
            const float* wr = wcp + (HXD + k) * HXD;
            float4 wv0 = *reinterpret_cast<const float4*>(wr + 0);
            float4 wv1 = *reinterpret_cast<const float4*>(wr + 4);
            acc[0] = fmaf(ci, wv0.x, acc[0]);
            acc[1] = fmaf(ci, wv0.y, acc[1]);
            acc[2] = fmaf(ci, wv0.z, acc[2]);
            acc[3] = fmaf(ci, wv0.w, acc[3]);
            acc[4] = fmaf(ci, wv1.x, acc[4]);
            acc[5] = fmaf(ci, wv1.y, acc[5]);
            acc[6] = fmaf(ci, wv1.z, acc[6]);
            acc[7] = fmaf(ci, wv1.w, acc[7]);
        }
        // tanh + decoder partial over this lane's 8 h-dims
        float qv[NACTD];
        #pragma unroll
        for (int o = 0; o < NACTD; ++o) qv[o] = 0.0f;
        const float* __restrict__ wdp = Wd + a * (HXD * NACTD) + og * 8 * NACTD;
        #pragma unroll
        for (int i = 0; i < 8; ++i) {
            float h2 = tanhf(acc[i]);
            #pragma unroll
            for (int o = 0; o < NACTD; ++o)
                qv[o] = fmaf(h2, wdp[i * NACTD + o], qv[o]);
        }
        // reduce across the 8 og groups (lane bits 3..5)
        #pragma unroll
        for (int o = 0; o < NACTD; ++o) {
            qv[o] += __shfl_xor(qv[o], 8, 64);
            qv[o] += __shfl_xor(qv[o], 16, 64);
            qv[o] += __shfl_xor(qv[o], 32, 64);
        }
        if (og == 0) {
            float* op = out + ((size_t)(b0 + lb) * NAGENTS + a) * NACTD;
            const float* bdp = bd + a * NACTD;
            #pragma unroll
            for (int o = 0; o < NACTD; ++o) op[o] = qv[o] + bdp[o];
        }
    }
}

extern "C" void kernel_launch(void* const* d_in, const int* in_sizes, int n_in,
                              void* d_out, int out_size, void* d_ws, size_t ws_size,
                              hipStream_t stream) {
    (void)d_ws; (void)ws_size; (void)out_size;
    if (n_in < 9) return;
    const float* obs = (const float*)d_in[0];
    const float* W1  = (const float*)d_in[1];
    const float* b1v = (const float*)d_in[2];
    const float* W2  = (const float*)d_in[3];
    const float* b2v = (const float*)d_in[4];
    const float* Wc  = (const float*)d_in[5];
    const float* bcv = (const float*)d_in[6];
    const float* Wd  = (const float*)d_in[7];
    const float* bdv = (const float*)d_in[8];
    float* out = (float*)d_out;
    const int Btot = in_sizes[0] / (NAGENTS * NOBSV);  // 16384
    dim3 grid(Btot / TBATCH), block(NTHREADS);
    qnet_fused<<<grid, block, 0, stream>>>(obs, W1, b1v, W2, b2v, Wc, bcv, Wd, bdv, out);
}

// Round 4
// 5629.693 us; speedup vs baseline: 1.2197x; 1.2197x over previous
//
#include <hip/hip_runtime.h>

#define NAGENTS 32
#define NOBSV   2
#define H1D     128
#define HXD     64
#define NACTD   5
#define TBATCH  8
#define NTHREADS 256
#define HSTRIDE (NAGENTS * HXD + 4)   // 2052 floats per batch row

// 256 threads = 4 waves. Wave w owns agents 8w..8w+7.
// lane = og*8 + lb: og in 0..7 (8-output slice), lb in 0..7 (batch-in-tile).
// Phase-1 ownership: thread tid = p_a*8 + p_b  ->  (p_a = wave*8+og, p_b = lb).
// LDS: s_obs 2.1 KB + s_hid 65.7 KB -> ~68 KB -> 2 blocks/CU (8 waves).
// No per-thread array larger than 8 floats is ever live -> no scratch spill.
__global__ __launch_bounds__(NTHREADS, 2) void qnet_fused(
    const float* __restrict__ obs,
    const float* __restrict__ W1, const float* __restrict__ b1,
    const float* __restrict__ W2, const float* __restrict__ b2,
    const float* __restrict__ Wc, const float* __restrict__ bc,
    const float* __restrict__ Wd, const float* __restrict__ bd,
    float* __restrict__ out)
{
    __shared__ float s_obs[TBATCH][NAGENTS * 2 + 2];
    __shared__ float s_hid[TBATCH * HSTRIDE];

    const int tid  = threadIdx.x;
    const int wave = tid >> 6;        // 0..3
    const int lane = tid & 63;
    const int lb   = lane & 7;        // batch-in-tile
    const int og   = lane >> 3;       // out-group (8 outputs)
    const int b0   = blockIdx.x * TBATCH;

    // ---- load obs tile: 8 x 32 x 2 floats = 512 floats, one float2/thread ----
    {
        const float2* src = reinterpret_cast<const float2*>(obs + (size_t)b0 * (NAGENTS * NOBSV));
        float2 v = src[tid];
        s_obs[tid >> 5][(tid & 31) * 2 + 0] = v.x;
        s_obs[tid >> 5][(tid & 31) * 2 + 1] = v.y;
    }
    __syncthreads();

    // ---- phase 1: neighbor mask for (p_a, p_b) in FLOAT64 (bit-matches the
    //      numpy-f64 reference: all intermediates exact in f64). ----
    const int p_a = tid >> 3;    // 0..31
    const int p_b = tid & 7;     // 0..7
    unsigned int bits = 0u;
    float Jf;
    {
        const double xi = (double)s_obs[p_b][p_a * 2 + 0] * 2.0;
        const double yi = (double)s_obs[p_b][p_a * 2 + 1] * 6.0;
        #pragma unroll
        for (int j = 0; j < NAGENTS; ++j) {
            double xj = (double)s_obs[p_b][j * 2 + 0] * 2.0;
            double yj = (double)s_obs[p_b][j * 2 + 1] * 6.0;
            double d = fabs(xi - xj) + fabs(yi - yj);
            if (d > 0.0 && d < 2.0) bits |= (1u << j);
        }
        Jf = fmaxf((float)__popc(bits), 1.0f);
    }

    // ---- phase 2: encoder MLP -> s_hid (f32). Wave w, iter ai -> agent 8w+ai. ----
    #pragma unroll 1
    for (int ai = 0; ai < 8; ++ai) {
        const int a = wave * 8 + ai;
        const float o0 = s_obs[lb][a * 2 + 0];
        const float o1 = s_obs[lb][a * 2 + 1];
        const float* __restrict__ w1p = W1 + a * (NOBSV * H1D);
        const float* __restrict__ b1p = b1 + a * H1D;
        const float* __restrict__ w2p = W2 + a * (H1D * HXD) + og * 8;
        const float* __restrict__ b2p = b2 + a * HXD + og * 8;
        float acc[8];
        {
            float4 bv0 = *reinterpret_cast<const float4*>(b2p + 0);
            float4 bv1 = *reinterpret_cast<const float4*>(b2p + 4);
            acc[0] = bv0.x; acc[1] = bv0.y; acc[2] = bv0.z; acc[3] = bv0.w;
            acc[4] = bv1.x; acc[5] = bv1.y; acc[6] = bv1.z; acc[7] = bv1.w;
        }
        #pragma unroll 4
        for (int k = 0; k < H1D; ++k) {
            float w0  = w1p[k];
            float w1v = w1p[H1D + k];
            float bb  = b1p[k];
            float h = fmaxf(fmaf(o1, w1v, fmaf(o0, w0, bb)), 0.0f);
            const float* wr = w2p + k * HXD;
            float4 wv0 = *reinterpret_cast<const float4*>(wr + 0);
            float4 wv1 = *reinterpret_cast<const float4*>(wr + 4);
            acc[0] = fmaf(h, wv0.x, acc[0]);
            acc[1] = fmaf(h, wv0.y, acc[1]);
            acc[2] = fmaf(h, wv0.z, acc[2]);
            acc[3] = fmaf(h, wv0.w, acc[3]);
            acc[4] = fmaf(h, wv1.x, acc[4]);
            acc[5] = fmaf(h, wv1.y, acc[5]);
            acc[6] = fmaf(h, wv1.z, acc[6]);
            acc[7] = fmaf(h, wv1.w, acc[7]);
        }
        float* dst = &s_hid[lb * HSTRIDE + a * HXD + og * 8];
        *reinterpret_cast<float4*>(dst + 0) =
            make_float4(fmaxf(acc[0],0.f), fmaxf(acc[1],0.f), fmaxf(acc[2],0.f), fmaxf(acc[3],0.f));
        *reinterpret_cast<float4*>(dst + 4) =
            make_float4(fmaxf(acc[4],0.f), fmaxf(acc[5],0.f), fmaxf(acc[6],0.f), fmaxf(acc[7],0.f));
    }
    __syncthreads();

    // ---- phase 3+4 fused, per agent: comms slice (8 regs) -> comm MLP -> decoder.
    //      Lane (og,lb) for agent a: cm8 = comms(b=lb, a)[og*8 .. og*8+8). ----
    #pragma unroll 1
    for (int ai = 0; ai < 8; ++ai) {
        const int a = wave * 8 + ai;
        const int srcm = ai * 8 + lb;                    // owner of mask(a, lb)
        const unsigned int mbits = (unsigned int)__shfl((int)bits, srcm, 64);
        const float Jv = __shfl(Jf, srcm, 64);

        float cm8[8];
        #pragma unroll
        for (int i = 0; i < 8; ++i) cm8[i] = 0.0f;
        {
            const float* hrow = &s_hid[lb * HSTRIDE + og * 8];
            #pragma unroll 4
            for (int j = 0; j < NAGENTS; ++j) {
                if ((mbits >> j) & 1u) {
                    const float4* hp = reinterpret_cast<const float4*>(hrow + j * HXD);
                    float4 v0 = hp[0];
                    float4 v1 = hp[1];
                    cm8[0] += v0.x; cm8[1] += v0.y; cm8[2] += v0.z; cm8[3] += v0.w;
                    cm8[4] += v1.x; cm8[5] += v1.y; cm8[6] += v1.z; cm8[7] += v1.w;
                }
            }
        }
        #pragma unroll
        for (int i = 0; i < 8; ++i) cm8[i] /= Jv;

        // comm MLP accumulators (outputs og*8 .. og*8+8)
        const float* __restrict__ wcp = Wc + a * (2 * HXD * HXD) + og * 8;
        const float* __restrict__ bcp = bc + a * HXD + og * 8;
        float acc[8];
        {
            float4 bv0 = *reinterpret_cast<const float4*>(bcp + 0);
            float4 bv1 = *reinterpret_cast<const float4*>(bcp + 4);
            acc[0] = bv0.x; acc[1] = bv0.y; acc[2] = bv0.z; acc[3] = bv0.w;
            acc[4] = bv1.x; acc[5] = bv1.y; acc[6] = bv1.z; acc[7] = bv1.w;
        }
        const int hbase = lb * HSTRIDE + a * HXD;
        // k = 0..63 : comm_input first half = hidden (LDS broadcast)
        #pragma unroll 4
        for (int k = 0; k < HXD; ++k) {
            const float ci = s_hid[hbase + k];
            const float* wr = wcp + k * HXD;
            float4 wv0 = *reinterpret_cast<const float4*>(wr + 0);
            float4 wv1 = *reinterpret_cast<const float4*>(wr + 4);
            acc[0] = fmaf(ci, wv0.x, acc[0]);
            acc[1] = fmaf(ci, wv0.y, acc[1]);
            acc[2] = fmaf(ci, wv0.z, acc[2]);
            acc[3] = fmaf(ci, wv0.w, acc[3]);
            acc[4] = fmaf(ci, wv1.x, acc[4]);
            acc[5] = fmaf(ci, wv1.y, acc[5]);
            acc[6] = fmaf(ci, wv1.z, acc[6]);
            acc[7] = fmaf(ci, wv1.w, acc[7]);
        }
        // k = 64..127 : second half = comms via wave shuffle from slice owner
        //               lane (k>>3)*8 + lb. Fully unrolled (static cm8 index).
        #pragma unroll
        for (int k2 = 0; k2 < HXD; ++k2) {
            const float ci = __shfl(cm8[k2 & 7], (k2 >> 3) * 8 + lb, 64);
            const float* wr = wcp + (HXD + k2) * HXD;
            float4 wv0 = *reinterpret_cast<const float4*>(wr + 0);
            float4 wv1 = *reinterpret_cast<const float4*>(wr + 4);
            acc[0] = fmaf(ci, wv0.x, acc[0]);
            acc[1] = fmaf(ci, wv0.y, acc[1]);
            acc[2] = fmaf(ci, wv0.z, acc[2]);
            acc[3] = fmaf(ci, wv0.w, acc[3]);
            acc[4] = fmaf(ci, wv1.x, acc[4]);
            acc[5] = fmaf(ci, wv1.y, acc[5]);
            acc[6] = fmaf(ci, wv1.z, acc[6]);
            acc[7] = fmaf(ci, wv1.w, acc[7]);
        }
        // tanh + decoder partial over this lane's 8 h-dims
        float qv[NACTD];
        #pragma unroll
        for (int o = 0; o < NACTD; ++o) qv[o] = 0.0f;
        const float* __restrict__ wdp = Wd + a * (HXD * NACTD) + og * 8 * NACTD;
        #pragma unroll
        for (int i = 0; i < 8; ++i) {
            float h2 = tanhf(acc[i]);
            #pragma unroll
            for (int o = 0; o < NACTD; ++o)
                qv[o] = fmaf(h2, wdp[i * NACTD + o], qv[o]);
        }
        // reduce across the 8 og groups (lane bits 3..5)
        #pragma unroll
        for (int o = 0; o < NACTD; ++o) {
            qv[o] += __shfl_xor(qv[o], 8, 64);
            qv[o] += __shfl_xor(qv[o], 16, 64);
            qv[o] += __shfl_xor(qv[o], 32, 64);
        }
        if (og == 0) {
            float* op = out + ((size_t)(b0 + lb) * NAGENTS + a) * NACTD;
            const float* bdp = bd + a * NACTD;
            #pragma unroll
            for (int o = 0; o < NACTD; ++o) op[o] = qv[o] + bdp[o];
        }
    }
}

extern "C" void kernel_launch(void* const* d_in, const int* in_sizes, int n_in,
                              void* d_out, int out_size, void* d_ws, size_t ws_size,
                              hipStream_t stream) {
    (void)d_ws; (void)ws_size; (void)out_size;
    if (n_in < 9) return;
    const float* obs = (const float*)d_in[0];
    const float* W1  = (const float*)d_in[1];
    const float* b1v = (const float*)d_in[2];
    const float* W2  = (const float*)d_in[3];
    const float* b2v = (const float*)d_in[4];
    const float* Wc  = (const float*)d_in[5];
    const float* bcv = (const float*)d_in[6];
    const float* Wd  = (const float*)d_in[7];
    const float* bdv = (const float*)d_in[8];
    float* out = (float*)d_out;
    const int Btot = in_sizes[0] / (NAGENTS * NOBSV);  // 16384
    dim3 grid(Btot / TBATCH), block(NTHREADS);
    qnet_fused<<<grid, block, 0, stream>>>(obs, W1, b1v, W2, b2v, Wc, bcv, Wd, bdv, out);
}

// Round 5
// 1115.763 us; speedup vs baseline: 6.1541x; 5.0456x over previous
//
#include <hip/hip_runtime.h>

#define NAGENTS 32
#define NOBSV   2
#define H1D     128
#define HXD     64
#define NACTD   5
#define TBATCH  8
#define NTHREADS 256
#define NWAVES  4
#define HSTRIDE (NAGENTS * HXD + 4)   // 2052 floats per batch row
#define CMSTRIDE (HXD + 2)            // 66 floats: broadcast reads conflict-free

// 256 threads = 4 waves. Wave w owns agents 8w..8w+7.
// lane = og*8 + lb: og in 0..7 (8-output slice), lb in 0..7 (batch-in-tile).
// Phase-1 ownership: tid = p_a*8 + p_b -> (p_a = wave*8+og, p_b = lb).
// LDS: s_obs 2.1 KB + s_hid 65.7 KB + s_cmw 8.4 KB = 74.4 KB -> 2 blocks/CU.
// No per-thread array >8 floats with a long live range; comms go through a
// wave-private LDS buffer (runtime-indexed reads -> no giant unroll, no spill).
__global__ __launch_bounds__(NTHREADS, 2) void qnet_fused(
    const float* __restrict__ obs,
    const float* __restrict__ W1, const float* __restrict__ b1,
    const float* __restrict__ W2, const float* __restrict__ b2,
    const float* __restrict__ Wc, const float* __restrict__ bc,
    const float* __restrict__ Wd, const float* __restrict__ bd,
    float* __restrict__ out)
{
    __shared__ float s_obs[TBATCH][NAGENTS * 2 + 2];
    __shared__ float s_hid[TBATCH * HSTRIDE];
    __shared__ float s_cmw[NWAVES][TBATCH][CMSTRIDE];

    const int tid  = threadIdx.x;
    const int wave = tid >> 6;        // 0..3
    const int lane = tid & 63;
    const int lb   = lane & 7;        // batch-in-tile
    const int og   = lane >> 3;       // out-group (8 outputs)
    const int b0   = blockIdx.x * TBATCH;

    // ---- load obs tile: 8 x 32 x 2 floats = 512 floats, one float2/thread ----
    {
        const float2* src = reinterpret_cast<const float2*>(obs + (size_t)b0 * (NAGENTS * NOBSV));
        float2 v = src[tid];
        s_obs[tid >> 5][(tid & 31) * 2 + 0] = v.x;
        s_obs[tid >> 5][(tid & 31) * 2 + 1] = v.y;
    }
    __syncthreads();

    // ---- phase 1: neighbor mask for (p_a, p_b) in FLOAT64 (bit-matches the
    //      numpy-f64 reference: all intermediates exact in f64). ----
    const int p_a = tid >> 3;    // 0..31
    const int p_b = tid & 7;     // 0..7
    unsigned int bits = 0u;
    float Jf;
    {
        const double xi = (double)s_obs[p_b][p_a * 2 + 0] * 2.0;
        const double yi = (double)s_obs[p_b][p_a * 2 + 1] * 6.0;
        #pragma unroll
        for (int j = 0; j < NAGENTS; ++j) {
            double xj = (double)s_obs[p_b][j * 2 + 0] * 2.0;
            double yj = (double)s_obs[p_b][j * 2 + 1] * 6.0;
            double d = fabs(xi - xj) + fabs(yi - yj);
            if (d > 0.0 && d < 2.0) bits |= (1u << j);
        }
        Jf = fmaxf((float)__popc(bits), 1.0f);
    }

    // ---- phase 2: encoder MLP -> s_hid (f32). Wave w, iter ai -> agent 8w+ai. ----
    #pragma unroll 1
    for (int ai = 0; ai < 8; ++ai) {
        const int a = wave * 8 + ai;
        const float o0 = s_obs[lb][a * 2 + 0];
        const float o1 = s_obs[lb][a * 2 + 1];
        const float* __restrict__ w1p = W1 + a * (NOBSV * H1D);
        const float* __restrict__ b1p = b1 + a * H1D;
        const float* __restrict__ w2p = W2 + a * (H1D * HXD) + og * 8;
        const float* __restrict__ b2p = b2 + a * HXD + og * 8;
        float acc[8];
        {
            float4 bv0 = *reinterpret_cast<const float4*>(b2p + 0);
            float4 bv1 = *reinterpret_cast<const float4*>(b2p + 4);
            acc[0] = bv0.x; acc[1] = bv0.y; acc[2] = bv0.z; acc[3] = bv0.w;
            acc[4] = bv1.x; acc[5] = bv1.y; acc[6] = bv1.z; acc[7] = bv1.w;
        }
        #pragma unroll 4
        for (int k = 0; k < H1D; ++k) {
            float w0  = w1p[k];
            float w1v = w1p[H1D + k];
            float bb  = b1p[k];
            float h = fmaxf(fmaf(o1, w1v, fmaf(o0, w0, bb)), 0.0f);
            const float* wr = w2p + k * HXD;
            float4 wv0 = *reinterpret_cast<const float4*>(wr + 0);
            float4 wv1 = *reinterpret_cast<const float4*>(wr + 4);
            acc[0] = fmaf(h, wv0.x, acc[0]);
            acc[1] = fmaf(h, wv0.y, acc[1]);
            acc[2] = fmaf(h, wv0.z, acc[2]);
            acc[3] = fmaf(h, wv0.w, acc[3]);
            acc[4] = fmaf(h, wv1.x, acc[4]);
            acc[5] = fmaf(h, wv1.y, acc[5]);
            acc[6] = fmaf(h, wv1.z, acc[6]);
            acc[7] = fmaf(h, wv1.w, acc[7]);
        }
        float* dst = &s_hid[lb * HSTRIDE + a * HXD + og * 8];
        *reinterpret_cast<float4*>(dst + 0) =
            make_float4(fmaxf(acc[0],0.f), fmaxf(acc[1],0.f), fmaxf(acc[2],0.f), fmaxf(acc[3],0.f));
        *reinterpret_cast<float4*>(dst + 4) =
            make_float4(fmaxf(acc[4],0.f), fmaxf(acc[5],0.f), fmaxf(acc[6],0.f), fmaxf(acc[7],0.f));
    }
    __syncthreads();

    // ---- phase 3+4 fused per agent. comms slice (8 regs, short-lived) ->
    //      wave-private LDS staging -> comm MLP (runtime-indexed LDS reads). ----
    #pragma unroll 1
    for (int ai = 0; ai < 8; ++ai) {
        const int a = wave * 8 + ai;
        const int srcm = ai * 8 + lb;                    // wave-lane owning mask(a, lb)
        const unsigned int mbits = (unsigned int)__shfl((int)bits, srcm, 64);
        const float Jv = __shfl(Jf, srcm, 64);

        // cm8 = comms(b=lb, a)[og*8 .. og*8+8), branchless masked sum.
        // fmaf(m, h, c) with m in {0,1} is bit-identical to reference mask*h+c.
        float cm8[8];
        #pragma unroll
        for (int i = 0; i < 8; ++i) cm8[i] = 0.0f;
        {
            const float* hrow = &s_hid[lb * HSTRIDE + og * 8];
            #pragma unroll 4
            for (int j = 0; j < NAGENTS; ++j) {
                const float m = (float)((mbits >> j) & 1u);
                const float4* hp = reinterpret_cast<const float4*>(hrow + j * HXD);
                float4 v0 = hp[0];
                float4 v1 = hp[1];
                cm8[0] = fmaf(m, v0.x, cm8[0]);
                cm8[1] = fmaf(m, v0.y, cm8[1]);
                cm8[2] = fmaf(m, v0.z, cm8[2]);
                cm8[3] = fmaf(m, v0.w, cm8[3]);
                cm8[4] = fmaf(m, v1.x, cm8[4]);
                cm8[5] = fmaf(m, v1.y, cm8[5]);
                cm8[6] = fmaf(m, v1.z, cm8[6]);
                cm8[7] = fmaf(m, v1.w, cm8[7]);
            }
        }
        // stage comms slice into wave-private LDS (cm8 dies here)
        {
            float* cw = &s_cmw[wave][lb][og * 8];
            *reinterpret_cast<float4*>(cw + 0) =
                make_float4(cm8[0]/Jv, cm8[1]/Jv, cm8[2]/Jv, cm8[3]/Jv);
            *reinterpret_cast<float4*>(cw + 4) =
                make_float4(cm8[4]/Jv, cm8[5]/Jv, cm8[6]/Jv, cm8[7]/Jv);
        }
        // wave-internal visibility: all 64 lanes wrote, all will read own-wave data
        asm volatile("s_waitcnt lgkmcnt(0)" ::: "memory");

        // comm MLP accumulators (outputs og*8 .. og*8+8)
        const float* __restrict__ wcp = Wc + a * (2 * HXD * HXD) + og * 8;
        const float* __restrict__ bcp = bc + a * HXD + og * 8;
        float acc[8];
        {
            float4 bv0 = *reinterpret_cast<const float4*>(bcp + 0);
            float4 bv1 = *reinterpret_cast<const float4*>(bcp + 4);
            acc[0] = bv0.x; acc[1] = bv0.y; acc[2] = bv0.z; acc[3] = bv0.w;
            acc[4] = bv1.x; acc[5] = bv1.y; acc[6] = bv1.z; acc[7] = bv1.w;
        }
        const int hbase = lb * HSTRIDE + a * HXD;
        // k = 0..63 : comm_input first half = hidden (LDS broadcast)
        #pragma unroll 4
        for (int k = 0; k < HXD; ++k) {
            const float ci = s_hid[hbase + k];
            const float* wr = wcp + k * HXD;
            float4 wv0 = *reinterpret_cast<const float4*>(wr + 0);
            float4 wv1 = *reinterpret_cast<const float4*>(wr + 4);
            acc[0] = fmaf(ci, wv0.x, acc[0]);
            acc[1] = fmaf(ci, wv0.y, acc[1]);
            acc[2] = fmaf(ci, wv0.z, acc[2]);
            acc[3] = fmaf(ci, wv0.w, acc[3]);
            acc[4] = fmaf(ci, wv1.x, acc[4]);
            acc[5] = fmaf(ci, wv1.y, acc[5]);
            acc[6] = fmaf(ci, wv1.z, acc[6]);
            acc[7] = fmaf(ci, wv1.w, acc[7]);
        }
        // k = 64..127 : second half = comms from wave-private LDS (broadcast,
        // stride-66 rows -> conflict-free). Runtime k index: no unroll pressure.
        #pragma unroll 4
        for (int k2 = 0; k2 < HXD; ++k2) {
            const float ci = s_cmw[wave][lb][k2];
            const float* wr = wcp + (HXD + k2) * HXD;
            float4 wv0 = *reinterpret_cast<const float4*>(wr + 0);
            float4 wv1 = *reinterpret_cast<const float4*>(wr + 4);
            acc[0] = fmaf(ci, wv0.x, acc[0]);
            acc[1] = fmaf(ci, wv0.y, acc[1]);
            acc[2] = fmaf(ci, wv0.z, acc[2]);
            acc[3] = fmaf(ci, wv0.w, acc[3]);
            acc[4] = fmaf(ci, wv1.x, acc[4]);
            acc[5] = fmaf(ci, wv1.y, acc[5]);
            acc[6] = fmaf(ci, wv1.z, acc[6]);
            acc[7] = fmaf(ci, wv1.w, acc[7]);
        }
        // tanh + decoder partial over this lane's 8 h-dims
        float qv[NACTD];
        #pragma unroll
        for (int o = 0; o < NACTD; ++o) qv[o] = 0.0f;
        const float* __restrict__ wdp = Wd + a * (HXD * NACTD) + og * 8 * NACTD;
        #pragma unroll
        for (int i = 0; i < 8; ++i) {
            float h2 = tanhf(acc[i]);
            #pragma unroll
            for (int o = 0; o < NACTD; ++o)
                qv[o] = fmaf(h2, wdp[i * NACTD + o], qv[o]);
        }
        // reduce across the 8 og groups (lane bits 3..5)
        #pragma unroll
        for (int o = 0; o < NACTD; ++o) {
            qv[o] += __shfl_xor(qv[o], 8, 64);
            qv[o] += __shfl_xor(qv[o], 16, 64);
            qv[o] += __shfl_xor(qv[o], 32, 64);
        }
        if (og == 0) {
            float* op = out + ((size_t)(b0 + lb) * NAGENTS + a) * NACTD;
            const float* bdp = bd + a * NACTD;
            #pragma unroll
            for (int o = 0; o < NACTD; ++o) op[o] = qv[o] + bdp[o];
        }
        // next iteration overwrites s_cmw[wave][..] — wave-private, and the
        // lgkmcnt(0) above orders this iteration's reads before next writes
        // only within the wave, which is the only consumer. Reads complete
        // before the next ds_write issues (in-order LDS pipe per wave).
    }
}

extern "C" void kernel_launch(void* const* d_in, const int* in_sizes, int n_in,
                              void* d_out, int out_size, void* d_ws, size_t ws_size,
                              hipStream_t stream) {
    (void)d_ws; (void)ws_size; (void)out_size;
    if (n_in < 9) return;
    const float* obs = (const float*)d_in[0];
    const float* W1  = (const float*)d_in[1];
    const float* b1v = (const float*)d_in[2];
    const float* W2  = (const float*)d_in[3];
    const float* b2v = (const float*)d_in[4];
    const float* Wc  = (const float*)d_in[5];
    const float* bcv = (const float*)d_in[6];
    const float* Wd  = (const float*)d_in[7];
    const float* bdv = (const float*)d_in[8];
    float* out = (float*)d_out;
    const int Btot = in_sizes[0] / (NAGENTS * NOBSV);  // 16384
    dim3 grid(Btot / TBATCH), block(NTHREADS);
    qnet_fused<<<grid, block, 0, stream>>>(obs, W1, b1v, W2, b2v, Wc, bcv, Wd, bdv, out);
}

// Round 6
// 990.869 us; speedup vs baseline: 6.9298x; 1.1260x over previous
//
#include <hip/hip_runtime.h>

#define NAGENTS 32
#define NOBSV   2
#define H1D     128
#define HXD     64
#define NACTD   5
#define TBATCH  8
#define NTHREADS 256
#define NWAVES  4
#define BFST    2056    // _Float16 elems per batch row of s_hid (32*64 + 8 pad)
#define HROWST  132     // s_h row stride in floats (128 + 4 pad -> bank spread)

typedef _Float16 half8 __attribute__((ext_vector_type(8)));

// 256 threads = 4 waves. Wave w owns agents 8w..8w+7.
// lane = og*8 + lb: og in 0..7 (8-out slice / 16-wide h slice), lb in 0..7 (batch).
// Phase-1 ownership: tid = p_a*8 + p_b -> (p_a = wave*8+og, p_b = lb).
// LDS: s_obs 2.1 KB + s_hid(f16) 32.9 KB + s_h 16.9 KB = 50.7 KB -> 3 blocks/CU.
// s_h is wave-private dual-use: phase-2 h staging, phase-3/4 comms staging.
__global__ __launch_bounds__(NTHREADS, 3) void qnet_fused(
    const float* __restrict__ obs,
    const float* __restrict__ W1, const float* __restrict__ b1,
    const float* __restrict__ W2, const float* __restrict__ b2,
    const float* __restrict__ Wc, const float* __restrict__ bc,
    const float* __restrict__ Wd, const float* __restrict__ bd,
    float* __restrict__ out)
{
    __shared__ float    s_obs[TBATCH][NAGENTS * 2 + 2];
    __shared__ _Float16 s_hid[TBATCH * BFST];
    __shared__ float    s_h[NWAVES][TBATCH][HROWST];

    const int tid  = threadIdx.x;
    const int wave = tid >> 6;        // 0..3
    const int lane = tid & 63;
    const int lb   = lane & 7;        // batch-in-tile
    const int og   = lane >> 3;       // out-group
    const int b0   = blockIdx.x * TBATCH;

    // ---- load obs tile: 8 x 32 x 2 floats = 512 floats, one float2/thread ----
    {
        const float2* src = reinterpret_cast<const float2*>(obs + (size_t)b0 * (NAGENTS * NOBSV));
        float2 v = src[tid];
        s_obs[tid >> 5][(tid & 31) * 2 + 0] = v.x;
        s_obs[tid >> 5][(tid & 31) * 2 + 1] = v.y;
    }
    __syncthreads();

    // ---- phase 1: neighbor mask for (p_a, p_b) in FLOAT64 (bit-matches the
    //      numpy-f64 reference; all intermediates exact in f64). ----
    const int p_a = tid >> 3;
    const int p_b = tid & 7;
    unsigned int bits = 0u;
    float Jf;
    {
        const double xi = (double)s_obs[p_b][p_a * 2 + 0] * 2.0;
        const double yi = (double)s_obs[p_b][p_a * 2 + 1] * 6.0;
        #pragma unroll
        for (int j = 0; j < NAGENTS; ++j) {
            double xj = (double)s_obs[p_b][j * 2 + 0] * 2.0;
            double yj = (double)s_obs[p_b][j * 2 + 1] * 6.0;
            double d = fabs(xi - xj) + fabs(yi - yj);
            if (d > 0.0 && d < 2.0) bits |= (1u << j);
        }
        Jf = fmaxf((float)__popc(bits), 1.0f);
    }

    // ---- phase 2: encoder. Cooperative h (each lane computes 16 of 128 h values,
    //      staged f32 in wave-private s_h -> bit-identical to per-lane recompute),
    //      then W2 GEMM streamed from L2, hidden packed to f16 in s_hid. ----
    #pragma unroll 1
    for (int ai = 0; ai < 8; ++ai) {
        const int a = wave * 8 + ai;
        const float o0 = s_obs[lb][a * 2 + 0];
        const float o1 = s_obs[lb][a * 2 + 1];
        {
            const float* __restrict__ w1a = W1 + a * (NOBSV * H1D) + og * 16;
            const float* __restrict__ w1b = w1a + H1D;
            const float* __restrict__ b1p = b1 + a * H1D + og * 16;
            float* hdst = &s_h[wave][lb][og * 16];
            #pragma unroll
            for (int c = 0; c < 4; ++c) {
                float4 wa = *reinterpret_cast<const float4*>(w1a + 4 * c);
                float4 wb = *reinterpret_cast<const float4*>(w1b + 4 * c);
                float4 bv = *reinterpret_cast<const float4*>(b1p + 4 * c);
                float4 hv;
                hv.x = fmaxf(fmaf(o1, wb.x, fmaf(o0, wa.x, bv.x)), 0.0f);
                hv.y = fmaxf(fmaf(o1, wb.y, fmaf(o0, wa.y, bv.y)), 0.0f);
                hv.z = fmaxf(fmaf(o1, wb.z, fmaf(o0, wa.z, bv.z)), 0.0f);
                hv.w = fmaxf(fmaf(o1, wb.w, fmaf(o0, wa.w, bv.w)), 0.0f);
                *reinterpret_cast<float4*>(hdst + 4 * c) = hv;
            }
        }
        asm volatile("s_waitcnt lgkmcnt(0)" ::: "memory");
        __builtin_amdgcn_sched_barrier(0);

        const float* __restrict__ w2p = W2 + a * (H1D * HXD) + og * 8;
        const float* __restrict__ b2p = b2 + a * HXD + og * 8;
        float acc[8];
        {
            float4 bv0 = *reinterpret_cast<const float4*>(b2p + 0);
            float4 bv1 = *reinterpret_cast<const float4*>(b2p + 4);
            acc[0] = bv0.x; acc[1] = bv0.y; acc[2] = bv0.z; acc[3] = bv0.w;
            acc[4] = bv1.x; acc[5] = bv1.y; acc[6] = bv1.z; acc[7] = bv1.w;
        }
        const float* hsrc = &s_h[wave][lb][0];
        #pragma unroll 8
        for (int k = 0; k < H1D; ++k) {
            const float hv = hsrc[k];
            const float* wr = w2p + k * HXD;
            float4 wv0 = *reinterpret_cast<const float4*>(wr + 0);
            float4 wv1 = *reinterpret_cast<const float4*>(wr + 4);
            acc[0] = fmaf(hv, wv0.x, acc[0]);
            acc[1] = fmaf(hv, wv0.y, acc[1]);
            acc[2] = fmaf(hv, wv0.z, acc[2]);
            acc[3] = fmaf(hv, wv0.w, acc[3]);
            acc[4] = fmaf(hv, wv1.x, acc[4]);
            acc[5] = fmaf(hv, wv1.y, acc[5]);
            acc[6] = fmaf(hv, wv1.z, acc[6]);
            acc[7] = fmaf(hv, wv1.w, acc[7]);
        }
        half8 hh;
        #pragma unroll
        for (int i = 0; i < 8; ++i) hh[i] = (_Float16)fmaxf(acc[i], 0.0f);
        *reinterpret_cast<half8*>(&s_hid[lb * BFST + a * HXD + og * 8]) = hh;
    }
    __syncthreads();

    // ---- phase 3+4 fused per agent: comms slice -> wave-private staging ->
    //      comm MLP (Wc streamed from L2) -> tanh -> decoder. ----
    #pragma unroll 1
    for (int ai = 0; ai < 8; ++ai) {
        const int a = wave * 8 + ai;
        const int srcm = ai * 8 + lb;
        const unsigned int mbits = (unsigned int)__shfl((int)bits, srcm, 64);
        const float Jv = __shfl(Jf, srcm, 64);

        // cm8 = comms(b=lb, a)[og*8 .. og*8+8), branchless masked sum (m in {0,1})
        float cm8[8];
        #pragma unroll
        for (int i = 0; i < 8; ++i) cm8[i] = 0.0f;
        {
            const _Float16* hrow = &s_hid[lb * BFST + og * 8];
            #pragma unroll 4
            for (int j = 0; j < NAGENTS; ++j) {
                const float m = (float)((mbits >> j) & 1u);
                half8 v = *reinterpret_cast<const half8*>(hrow + j * HXD);
                cm8[0] = fmaf(m, (float)v[0], cm8[0]);
                cm8[1] = fmaf(m, (float)v[1], cm8[1]);
                cm8[2] = fmaf(m, (float)v[2], cm8[2]);
                cm8[3] = fmaf(m, (float)v[3], cm8[3]);
                cm8[4] = fmaf(m, (float)v[4], cm8[4]);
                cm8[5] = fmaf(m, (float)v[5], cm8[5]);
                cm8[6] = fmaf(m, (float)v[6], cm8[6]);
                cm8[7] = fmaf(m, (float)v[7], cm8[7]);
            }
        }
        {
            float* cw = &s_h[wave][lb][og * 8];
            *reinterpret_cast<float4*>(cw + 0) =
                make_float4(cm8[0]/Jv, cm8[1]/Jv, cm8[2]/Jv, cm8[3]/Jv);
            *reinterpret_cast<float4*>(cw + 4) =
                make_float4(cm8[4]/Jv, cm8[5]/Jv, cm8[6]/Jv, cm8[7]/Jv);
        }
        asm volatile("s_waitcnt lgkmcnt(0)" ::: "memory");
        __builtin_amdgcn_sched_barrier(0);

        const float* __restrict__ wcp = Wc + a * (2 * HXD * HXD) + og * 8;
        const float* __restrict__ bcp = bc + a * HXD + og * 8;
        float acc[8];
        {
            float4 bv0 = *reinterpret_cast<const float4*>(bcp + 0);
            float4 bv1 = *reinterpret_cast<const float4*>(bcp + 4);
            acc[0] = bv0.x; acc[1] = bv0.y; acc[2] = bv0.z; acc[3] = bv0.w;
            acc[4] = bv1.x; acc[5] = bv1.y; acc[6] = bv1.z; acc[7] = bv1.w;
        }
        const _Float16* hbase = &s_hid[lb * BFST + a * HXD];
        // k = 0..63 : first half = hidden (f16 LDS broadcast)
        #pragma unroll 8
        for (int k = 0; k < HXD; ++k) {
            const float ci = (float)hbase[k];
            const float* wr = wcp + k * HXD;
            float4 wv0 = *reinterpret_cast<const float4*>(wr + 0);
            float4 wv1 = *reinterpret_cast<const float4*>(wr + 4);
            acc[0] = fmaf(ci, wv0.x, acc[0]);
            acc[1] = fmaf(ci, wv0.y, acc[1]);
            acc[2] = fmaf(ci, wv0.z, acc[2]);
            acc[3] = fmaf(ci, wv0.w, acc[3]);
            acc[4] = fmaf(ci, wv1.x, acc[4]);
            acc[5] = fmaf(ci, wv1.y, acc[5]);
            acc[6] = fmaf(ci, wv1.z, acc[6]);
            acc[7] = fmaf(ci, wv1.w, acc[7]);
        }
        // k = 64..127 : second half = comms (f32, wave-private staging)
        #pragma unroll 8
        for (int k2 = 0; k2 < HXD; ++k2) {
            const float ci = s_h[wave][lb][k2];
            const float* wr = wcp + (HXD + k2) * HXD;
            float4 wv0 = *reinterpret_cast<const float4*>(wr + 0);
            float4 wv1 = *reinterpret_cast<const float4*>(wr + 4);
            acc[0] = fmaf(ci, wv0.x, acc[0]);
            acc[1] = fmaf(ci, wv0.y, acc[1]);
            acc[2] = fmaf(ci, wv0.z, acc[2]);
            acc[3] = fmaf(ci, wv0.w, acc[3]);
            acc[4] = fmaf(ci, wv1.x, acc[4]);
            acc[5] = fmaf(ci, wv1.y, acc[5]);
            acc[6] = fmaf(ci, wv1.z, acc[6]);
            acc[7] = fmaf(ci, wv1.w, acc[7]);
        }
        // tanh + decoder partial over this lane's 8 h-dims
        float qv[NACTD];
        #pragma unroll
        for (int o = 0; o < NACTD; ++o) qv[o] = 0.0f;
        const float* __restrict__ wdp = Wd + a * (HXD * NACTD) + og * 8 * NACTD;
        #pragma unroll
        for (int i = 0; i < 8; ++i) {
            float h2 = tanhf(acc[i]);
            #pragma unroll
            for (int o = 0; o < NACTD; ++o)
                qv[o] = fmaf(h2, wdp[i * NACTD + o], qv[o]);
        }
        #pragma unroll
        for (int o = 0; o < NACTD; ++o) {
            qv[o] += __shfl_xor(qv[o], 8, 64);
            qv[o] += __shfl_xor(qv[o], 16, 64);
            qv[o] += __shfl_xor(qv[o], 32, 64);
        }
        if (og == 0) {
            float* op = out + ((size_t)(b0 + lb) * NAGENTS + a) * NACTD;
            const float* bdp = bd + a * NACTD;
            #pragma unroll
            for (int o = 0; o < NACTD; ++o) op[o] = qv[o] + bdp[o];
        }
    }
}

extern "C" void kernel_launch(void* const* d_in, const int* in_sizes, int n_in,
                              void* d_out, int out_size, void* d_ws, size_t ws_size,
                              hipStream_t stream) {
    (void)d_ws; (void)ws_size; (void)out_size;
    if (n_in < 9) return;
    const float* obs = (const float*)d_in[0];
    const float* W1  = (const float*)d_in[1];
    const float* b1v = (const float*)d_in[2];
    const float* W2  = (const float*)d_in[3];
    const float* b2v = (const float*)d_in[4];
    const float* Wc  = (const float*)d_in[5];
    const float* bcv = (const float*)d_in[6];
    const float* Wd  = (const float*)d_in[7];
    const float* bdv = (const float*)d_in[8];
    float* out = (float*)d_out;
    const int Btot = in_sizes[0] / (NAGENTS * NOBSV);  // 16384
    dim3 grid(Btot / TBATCH), block(NTHREADS);
    qnet_fused<<<grid, block, 0, stream>>>(obs, W1, b1v, W2, b2v, Wc, bcv, Wd, bdv, out);
}